// Round 2
// baseline (90810.071 us; speedup 1.0000x reference)
//
#include <hip/hip_runtime.h>
#include <stdint.h>
#include <math.h>

#define T_STEPS 512
#define BATCH   256
#define HID     512
#define KDIM    640
#define M_TILE  32
#define WGSZ    512
#define N_WG    256
#define A_STRIDE 644           // 640 + 4 pad: rr-groups land 4 banks apart
#define WCH     64             // k-chunk size for W streaming
#define NGC     64             // gate-cols per WG (16 j-cols x 4 gates)

typedef unsigned int u32;

#define WS_BAR_BYTES 4096
#define HBUF_ELEMS  (BATCH*HID)
#define BH          (BATCH*HID)
#define CS_OFF      ((size_t)T_STEPS*BATCH*HID)

__device__ __forceinline__ float sigm(float x) { return 1.0f / (1.0f + expf(-x)); }

extern "C" __global__ void __launch_bounds__(WGSZ, 2)
lstm_fp32(const float* __restrict__ xm, const float* __restrict__ xa,
          const float* __restrict__ Wf, const float* __restrict__ bfp,
          const float* __restrict__ Wi, const float* __restrict__ bip,
          const float* __restrict__ Wo, const float* __restrict__ bop,
          const float* __restrict__ Wp, const float* __restrict__ bpp,
          float* __restrict__ out, char* __restrict__ ws)
{
  // LDS: A 32x644 f32 (82432 B) + W double-buffered 64k x 64gc (2x16384 B) = 115200 B
  __shared__ __align__(16) float Alds[M_TILE * A_STRIDE];
  __shared__ __align__(16) float Wlds[2][WCH * NGC];

  const int tid = threadIdx.x;
  const int wg  = blockIdx.x;
  const int mg  = wg >> 5;         // cluster 0..7 (rows)
  const int jg  = wg & 31;         // j-slice 0..31 (jg%8 == XCD id -> W slice L2-local)
  const int b0  = mg * M_TILE;
  const int j0  = jg * 16;
  const int rr  = tid >> 4;        // 0..31 local row
  const int jl  = tid & 15;        // 0..15 local col

  u32* bar_cnt = (u32*)(ws + mg * 256);
  u32* bar_gen = bar_cnt + 16;
  float* hbuf0 = (float*)(ws + WS_BAR_BYTES);
  float* hbuf1 = hbuf0 + HBUF_ELEMS;

  const float* Wg[4] = {Wf, Wi, Wo, Wp};
  // W staging role for this thread (fixed): e_low = tid -> jl_w fastest, then gate, then kk
  const int jl_w = tid & 15;
  const int g_w  = (tid >> 4) & 3;
  const int kk_w0 = tid >> 6;          // 0..7, kk = kk_w0 + 8*s
  const float* Wsrc = Wg[g_w];

  float bias_f = bfp[j0 + jl];
  float bias_i = bip[j0 + jl];
  float bias_o = bop[j0 + jl];
  float bias_p = bpp[j0 + jl];

  float cst = 0.0f;                    // persistent c for cell (b0+rr, j0+jl)

  for (int t = 0; t < T_STEPS; ++t) {
    const float* hread  = (t & 1) ? hbuf1 : hbuf0;
    float*       hwrite = (t & 1) ? hbuf0 : hbuf1;

    // ---- stage A = [x_t | h_prev], rows b0..b0+31, 160 float4 per row ----
    #pragma unroll
    for (int s = 0; s < 10; ++s) {
      int slot = s * WGSZ + tid;       // 0..5119
      int r  = slot / 160;
      int c4 = slot - r * 160;
      int b  = b0 + r;
      float4 v;
      if (c4 < 32) {
        const float* src = (c4 < 16)
          ? (xm + ((size_t)t * BATCH + b) * 64 + c4 * 4)
          : (xa + ((size_t)t * BATCH + b) * 64 + (c4 - 16) * 4);
        v = *(const float4*)src;
      } else {
        v = *(const float4*)(hread + (size_t)b * HID + (c4 - 32) * 4);
      }
      *(float4*)&Alds[r * A_STRIDE + c4 * 4] = v;
    }

    // ---- stage W chunk 0 ----
    {
      float wv[8];
      #pragma unroll
      for (int s = 0; s < 8; ++s) {
        int kk = kk_w0 + 8 * s;
        wv[s] = Wsrc[(size_t)kk * HID + j0 + jl_w];
      }
      #pragma unroll
      for (int s = 0; s < 8; ++s) {
        int kk = kk_w0 + 8 * s;
        Wlds[0][kk * NGC + jl_w * 4 + g_w] = wv[s];
      }
    }
    __syncthreads();

    float accf = 0.f, acci = 0.f, acco = 0.f, accp = 0.f;

    for (int kb = 0; kb < 10; ++kb) {
      // prefetch next W chunk (global loads in flight during compute)
      float wv[8];
      if (kb < 9) {
        int k0n = (kb + 1) * WCH;
        #pragma unroll
        for (int s = 0; s < 8; ++s) {
          int kk = kk_w0 + 8 * s;
          wv[s] = Wsrc[(size_t)(k0n + kk) * HID + j0 + jl_w];
        }
      }

      const int k0 = kb * WCH;
      const float* wl = &Wlds[kb & 1][jl * 4];
      const float* al = &Alds[rr * A_STRIDE + k0];
      #pragma unroll
      for (int kk4 = 0; kk4 < 16; ++kk4) {
        float4 a4 = *(const float4*)(al + kk4 * 4);
        float a[4] = {a4.x, a4.y, a4.z, a4.w};
        #pragma unroll
        for (int e = 0; e < 4; ++e) {
          float4 w4 = *(const float4*)(wl + (kk4 * 4 + e) * NGC);
          accf = fmaf(a[e], w4.x, accf);
          acci = fmaf(a[e], w4.y, acci);
          acco = fmaf(a[e], w4.z, acco);
          accp = fmaf(a[e], w4.w, accp);
        }
      }

      if (kb < 9) {
        int buf = (kb + 1) & 1;
        #pragma unroll
        for (int s = 0; s < 8; ++s) {
          int kk = kk_w0 + 8 * s;
          Wlds[buf][kk * NGC + jl_w * 4 + g_w] = wv[s];
        }
      }
      __syncthreads();
    }

    // ---- LSTM cell (one cell per thread, no reduction) ----
    {
      int b = b0 + rr;
      int j = j0 + jl;
      float f = sigm(accf + bias_f);
      float i = sigm(acci + bias_i);
      float o = sigm(acco + bias_o);
      float p = tanhf(accp + bias_p);
      float cn = f * cst + i * p;
      cst = cn;
      float h = o * tanhf(cn);
      size_t idx = (size_t)t * BH + (size_t)b * HID + j;
      out[idx] = h;
      out[CS_OFF + idx] = cn;
      hwrite[(size_t)b * HID + j] = h;
    }

    // ---- cluster barrier (32 WGs of this m-group), device scope ----
    __syncthreads();
    if (tid == 0) {
      __builtin_amdgcn_fence(__ATOMIC_RELEASE, "agent");
      u32 ret = __hip_atomic_fetch_add(bar_cnt, 1u, __ATOMIC_RELAXED, __HIP_MEMORY_SCOPE_AGENT);
      u32 target = (u32)(32 * (t + 1));
      if (ret == target - 1) {
        __hip_atomic_store(bar_gen, (u32)(t + 1), __ATOMIC_RELEASE, __HIP_MEMORY_SCOPE_AGENT);
      } else {
        while (__hip_atomic_load(bar_gen, __ATOMIC_RELAXED, __HIP_MEMORY_SCOPE_AGENT) < (u32)(t + 1)) {
          __builtin_amdgcn_s_sleep(1);
        }
      }
      __builtin_amdgcn_fence(__ATOMIC_ACQUIRE, "agent");
    }
    __syncthreads();
  }
}

extern "C" void kernel_launch(void* const* d_in, const int* in_sizes, int n_in,
                              void* d_out, int out_size, void* d_ws, size_t ws_size,
                              hipStream_t stream) {
  const float* xm = (const float*)d_in[0];
  const float* xa = (const float*)d_in[1];
  const float* Wf = (const float*)d_in[2];
  const float* bf = (const float*)d_in[3];
  const float* Wi = (const float*)d_in[4];
  const float* bi = (const float*)d_in[5];
  const float* Wo = (const float*)d_in[6];
  const float* bo = (const float*)d_in[7];
  const float* Wp = (const float*)d_in[8];
  const float* bp = (const float*)d_in[9];
  float* out = (float*)d_out;
  char* ws = (char*)d_ws;

  // zero barrier lines + h ping buffer 0 (h0 = 0)
  hipMemsetAsync(d_ws, 0, WS_BAR_BYTES + (size_t)HBUF_ELEMS * sizeof(float), stream);

  void* args[] = { &xm, &xa, &Wf, &bf, &Wi, &bi, &Wo, &bo, &Wp, &bp, &out, &ws };
  dim3 grid(N_WG), block(WGSZ);
  hipError_t e = hipLaunchCooperativeKernel((const void*)lstm_fp32, grid, block,
                                            args, 0, stream);
  if (e != hipSuccess) {
    lstm_fp32<<<grid, block, 0, stream>>>(xm, xa, Wf, bf, Wi, bi, Wo, bo, Wp, bp, out, ws);
  }
}